// Round 2
// baseline (158.400 us; speedup 1.0000x reference)
//
#include <hip/hip_runtime.h>

// ---------------------------------------------------------------------------
// Compile-time Cayley tables for PGA G(3,0,1), basis ordered by grade:
// idx: 0:1 1:e0 2:e1 3:e2 4:e3 5:e01 6:e02 7:e03 8:e12 9:e13 10:e23
//      11:e012 12:e013 13:e023 14:e123 15:e0123
// Blade as 4-bit mask: e0=bit0, e1=bit1, e2=bit2, e3=bit3.
// ---------------------------------------------------------------------------
namespace ga {

constexpr int MASK[16]        = {0,1,2,4,8,3,5,9,6,10,12,7,11,13,14,15};
constexpr int IDX_OF_MASK[16] = {0,1,2,5,3,6,8,11,4,7,9,12,10,13,14,15};

constexpr int popc(int v) { int c = 0; while (v) { c += v & 1; v >>= 1; } return c; }

// Sign from reordering concatenation of sorted blades a,b into canonical order:
// (-1)^(# pairs (i in a, j in b) with i > j)
constexpr int reorder_sign(int a, int b) {
    int s = 0; int t = a >> 1;
    while (t) { s += popc(t & b); t >>= 1; }
    return (s & 1) ? -1 : 1;
}

struct Term { signed char i, j, k, s; };

// Geometric product, metric (0,1,1,1): zero iff both blades contain e0.
// 192 nonzero terms.
struct GPTab { Term t[192]; };
constexpr GPTab build_gp() {
    GPTab T{}; int n = 0;
    for (int i = 0; i < 16; i++)
        for (int j = 0; j < 16; j++) {
            int a = MASK[i], b = MASK[j];
            if (a & b & 1) continue;                 // e0^2 = 0
            T.t[n].i = (signed char)i;
            T.t[n].j = (signed char)j;
            T.t[n].k = (signed char)IDX_OF_MASK[a ^ b];
            T.t[n].s = (signed char)reorder_sign(a, b);  // shared e1..e3 square to +1
            n++;
        }
    return T;
}

// Join (without the ref scale): dual(dual(x) ^ dual(y)).
// Folded into one bilinear table: J[i,j,k] = s(i) s(j) s(d(k)) W[d(i),d(j),d(k)],
// where d = complement index map (involution), s = dual sign. 81 nonzero terms.
struct JNTab { Term t[81]; };
constexpr JNTab build_join() {
    JNTab T{}; int n = 0;
    int didx[16] = {}, dsgn[16] = {};
    for (int i = 0; i < 16; i++) {
        int a = MASK[i], c = (~a) & 0xF;
        didx[i] = IDX_OF_MASK[c];
        dsgn[i] = reorder_sign(a, c);   // e_a ^ (s*e_c) = +e0123
    }
    for (int i = 0; i < 16; i++)
        for (int j = 0; j < 16; j++) {
            int p = didx[i], q = didx[j];
            int a = MASK[p], b = MASK[q];
            if (a & b) continue;                      // wedge vanishes
            int m = IDX_OF_MASK[a | b];               // wedge output index
            int k = didx[m];                          // dual back out
            int s = dsgn[i] * dsgn[j] * dsgn[m] * reorder_sign(a, b);
            T.t[n].i = (signed char)i;
            T.t[n].j = (signed char)j;
            T.t[n].k = (signed char)k;
            T.t[n].s = (signed char)s;
            n++;
        }
    return T;
}

constexpr GPTab G = build_gp();
constexpr JNTab J = build_join();

} // namespace ga

// ---------------------------------------------------------------------------
// One thread per point. 64 B contiguous loads per thread (float4 x4) for x,y;
// scalar load of ref pseudoscalar; 32-float output via float4 x8 stores.
// Memory-bound: ~168 MB round trip -> ~27 us floor at 6.3 TB/s.
// ---------------------------------------------------------------------------
__global__ __launch_bounds__(256)
void MVGeometricBilinear_kernel(const float* __restrict__ x,
                                const float* __restrict__ y,
                                const float* __restrict__ ref,
                                float* __restrict__ out,
                                int npts)
{
    int pt = blockIdx.x * 256 + threadIdx.x;
    if (pt >= npts) return;

    const float4* xp = reinterpret_cast<const float4*>(x) + (size_t)pt * 4;
    const float4* yp = reinterpret_cast<const float4*>(y) + (size_t)pt * 4;

    float4 a0 = xp[0], a1 = xp[1], a2 = xp[2], a3 = xp[3];
    float4 b0 = yp[0], b1 = yp[1], b2 = yp[2], b3 = yp[3];
    float r = ref[(size_t)pt * 16 + 15];

    float xx[16] = {a0.x, a0.y, a0.z, a0.w, a1.x, a1.y, a1.z, a1.w,
                    a2.x, a2.y, a2.z, a2.w, a3.x, a3.y, a3.z, a3.w};
    float yy[16] = {b0.x, b0.y, b0.z, b0.w, b1.x, b1.y, b1.z, b1.w,
                    b2.x, b2.y, b2.z, b2.w, b3.x, b3.y, b3.z, b3.w};

    float gp[16] = {0.f, 0.f, 0.f, 0.f, 0.f, 0.f, 0.f, 0.f,
                    0.f, 0.f, 0.f, 0.f, 0.f, 0.f, 0.f, 0.f};
    float jn[16] = {0.f, 0.f, 0.f, 0.f, 0.f, 0.f, 0.f, 0.f,
                    0.f, 0.f, 0.f, 0.f, 0.f, 0.f, 0.f, 0.f};

#pragma unroll
    for (int t = 0; t < 192; t++) {
        const int ti = ga::G.t[t].i, tj = ga::G.t[t].j, tk = ga::G.t[t].k;
        const float v = xx[ti] * yy[tj];
        if (ga::G.t[t].s > 0) gp[tk] += v; else gp[tk] -= v;
    }
#pragma unroll
    for (int t = 0; t < 81; t++) {
        const int ti = ga::J.t[t].i, tj = ga::J.t[t].j, tk = ga::J.t[t].k;
        const float v = xx[ti] * yy[tj];
        if (ga::J.t[t].s > 0) jn[tk] += v; else jn[tk] -= v;
    }

    float4* op = reinterpret_cast<float4*>(out) + (size_t)pt * 8;
    op[0] = make_float4(gp[0],  gp[1],  gp[2],  gp[3]);
    op[1] = make_float4(gp[4],  gp[5],  gp[6],  gp[7]);
    op[2] = make_float4(gp[8],  gp[9],  gp[10], gp[11]);
    op[3] = make_float4(gp[12], gp[13], gp[14], gp[15]);
    op[4] = make_float4(r * jn[0],  r * jn[1],  r * jn[2],  r * jn[3]);
    op[5] = make_float4(r * jn[4],  r * jn[5],  r * jn[6],  r * jn[7]);
    op[6] = make_float4(r * jn[8],  r * jn[9],  r * jn[10], r * jn[11]);
    op[7] = make_float4(r * jn[12], r * jn[13], r * jn[14], r * jn[15]);
}

extern "C" void kernel_launch(void* const* d_in, const int* in_sizes, int n_in,
                              void* d_out, int out_size, void* d_ws, size_t ws_size,
                              hipStream_t stream) {
    const float* x   = (const float*)d_in[0];
    const float* y   = (const float*)d_in[1];
    const float* ref = (const float*)d_in[2];
    float* out = (float*)d_out;

    const int npts = in_sizes[0] / 16;           // B*T = 524288
    const int blocks = (npts + 255) / 256;

    MVGeometricBilinear_kernel<<<blocks, 256, 0, stream>>>(x, y, ref, out, npts);
}

// Round 4
// 149.330 us; speedup vs baseline: 1.0607x; 1.0607x over previous
//
#include <hip/hip_runtime.h>

// ---------------------------------------------------------------------------
// Compile-time Cayley tables for PGA G(3,0,1), basis ordered by grade:
// idx: 0:1 1:e0 2:e1 3:e2 4:e3 5:e01 6:e02 7:e03 8:e12 9:e13 10:e23
//      11:e012 12:e013 13:e023 14:e123 15:e0123
// Blade as 4-bit mask: e0=bit0, e1=bit1, e2=bit2, e3=bit3.
// ---------------------------------------------------------------------------
namespace ga {

constexpr int MASK[16]        = {0,1,2,4,8,3,5,9,6,10,12,7,11,13,14,15};
constexpr int IDX_OF_MASK[16] = {0,1,2,5,3,6,8,11,4,7,9,12,10,13,14,15};

constexpr int popc(int v) { int c = 0; while (v) { c += v & 1; v >>= 1; } return c; }

constexpr int reorder_sign(int a, int b) {
    int s = 0; int t = a >> 1;
    while (t) { s += popc(t & b); t >>= 1; }
    return (s & 1) ? -1 : 1;
}

struct Term { signed char i, j, k, s; };

// Geometric product, metric (0,1,1,1): 192 nonzero terms.
struct GPTab { Term t[192]; };
constexpr GPTab build_gp() {
    GPTab T{}; int n = 0;
    for (int i = 0; i < 16; i++)
        for (int j = 0; j < 16; j++) {
            int a = MASK[i], b = MASK[j];
            if (a & b & 1) continue;                 // e0^2 = 0
            T.t[n].i = (signed char)i;
            T.t[n].j = (signed char)j;
            T.t[n].k = (signed char)IDX_OF_MASK[a ^ b];
            T.t[n].s = (signed char)reorder_sign(a, b);
            n++;
        }
    return T;
}

// Join (sans ref scale): dual(dual(x) ^ dual(y)) folded to 81 terms.
struct JNTab { Term t[81]; };
constexpr JNTab build_join() {
    JNTab T{}; int n = 0;
    int didx[16] = {}, dsgn[16] = {};
    for (int i = 0; i < 16; i++) {
        int a = MASK[i], c = (~a) & 0xF;
        didx[i] = IDX_OF_MASK[c];
        dsgn[i] = reorder_sign(a, c);
    }
    for (int i = 0; i < 16; i++)
        for (int j = 0; j < 16; j++) {
            int p = didx[i], q = didx[j];
            int a = MASK[p], b = MASK[q];
            if (a & b) continue;
            int m = IDX_OF_MASK[a | b];
            int k = didx[m];
            int s = dsgn[i] * dsgn[j] * dsgn[m] * reorder_sign(a, b);
            T.t[n].i = (signed char)i;
            T.t[n].j = (signed char)j;
            T.t[n].k = (signed char)k;
            T.t[n].s = (signed char)s;
            n++;
        }
    return T;
}

constexpr GPTab G = build_gp();
constexpr JNTab J = build_join();

} // namespace ga

// ---------------------------------------------------------------------------
// Wave-private LDS staging; each wave owns 64 points. All global traffic is
// unit-stride float4 (16 lines/instr, 4 lanes/line) — fixes R2's
// 64-lines-per-instruction strided pattern that capped HBM at 30%.
//
// R3 post-mortem: `lo` overlays lx/ly, and lane L's lo-writes are PROVABLY
// DISJOINT (per-thread) from its ly-reads (16L = 1280+(a-b) has no solution
// for L<=63) — so the compiler may legally schedule ds_writes before the last
// ly ds_read, and lanes >=36 then clobber other lanes' y-data (cross-lane WAR
// invisible to per-thread alias analysis). Fix: __syncthreads() between frag
// reads and overlay writes — a scheduling fence LDS ops cannot cross.
//
// LDS layout per wave (floats):  lx[64][20] | ly[64][20] | lr[64]
//   stride 20 (80 B): b128 frag reads hit bank starts {0,20,8,28,16,4,24,12}
//   per 8-lane group -> 32 banks, conflict-free.
//   out overlay lo[64][36] (stride 144 B) over lx/ly: starts {0,4,..,28} ->
//   conflict-free; 64*36=2304 <= 2560 so lr is never touched.
// ---------------------------------------------------------------------------
constexpr int XSTRIDE = 20;
constexpr int OSTRIDE = 36;
constexpr int WAVE_FLOATS = 64 * XSTRIDE * 2 + 64;   // 2624 floats = 10.25 KB

__global__ __launch_bounds__(128)
void MVGeometricBilinear_kernel(const float* __restrict__ x,
                                const float* __restrict__ y,
                                const float* __restrict__ ref,
                                float* __restrict__ out,
                                int nwaves)
{
    __shared__ __align__(16) float lds[2 * WAVE_FLOATS];   // 21 KB -> 7 blk/CU

    const int wave = threadIdx.x >> 6;
    const int lane = threadIdx.x & 63;
    const long wid = (long)blockIdx.x * 2 + wave;
    const bool active = (wid < nwaves);

    float* wl = lds + wave * WAVE_FLOATS;
    float* lx = wl;                   // [64][20]
    float* ly = wl + 64 * XSTRIDE;    // [64][20]
    float* lr = wl + 128 * XSTRIDE;   // [64]
    float* lo = wl;                   // [64][36] overlay (valid after barrier)

    const long wbase = (active ? wid : 0) * 64;

    float xx[16], yy[16], r = 0.f;
    float gp[16] = {0.f, 0.f, 0.f, 0.f, 0.f, 0.f, 0.f, 0.f,
                    0.f, 0.f, 0.f, 0.f, 0.f, 0.f, 0.f, 0.f};
    float jn[16] = {0.f, 0.f, 0.f, 0.f, 0.f, 0.f, 0.f, 0.f,
                    0.f, 0.f, 0.f, 0.f, 0.f, 0.f, 0.f, 0.f};

    if (active) {
        // ---- stage: unit-stride float4 global -> LDS ----
        const float4* gx = reinterpret_cast<const float4*>(x)   + wbase * 4;
        const float4* gy = reinterpret_cast<const float4*>(y)   + wbase * 4;
        const float4* gr = reinterpret_cast<const float4*>(ref) + wbase * 4;
#pragma unroll
        for (int c = 0; c < 4; c++) {
            const int g  = lane + 64 * c;     // float4 index in wave span
            const int p  = g >> 2;            // point
            const int ch = g & 3;             // 16-B chunk within point
            const float4 vx = gx[g];
            const float4 vy = gy[g];
            const float4 vr = gr[g];
            *reinterpret_cast<float4*>(lx + p * XSTRIDE + ch * 4) = vx;
            *reinterpret_cast<float4*>(ly + p * XSTRIDE + ch * 4) = vy;
            if (ch == 3) lr[p] = vr.w;        // ref[16p+15]
        }
        // stage->read order is pinned without a barrier: the access pairs
        // may-alias per-thread, so the compiler preserves order; the LDS pipe
        // is in-order per wave.

        // ---- fragments: conflict-free b128 LDS reads ----
#pragma unroll
        for (int k = 0; k < 4; k++) {
            const float4 vx = *reinterpret_cast<const float4*>(lx + lane * XSTRIDE + k * 4);
            const float4 vy = *reinterpret_cast<const float4*>(ly + lane * XSTRIDE + k * 4);
            xx[4*k+0] = vx.x; xx[4*k+1] = vx.y; xx[4*k+2] = vx.z; xx[4*k+3] = vx.w;
            yy[4*k+0] = vy.x; yy[4*k+1] = vy.y; yy[4*k+2] = vy.z; yy[4*k+3] = vy.w;
        }
        r = lr[lane];

        // ---- compute ----
#pragma unroll
        for (int t = 0; t < 192; t++) {
            const int ti = ga::G.t[t].i, tj = ga::G.t[t].j, tk = ga::G.t[t].k;
            const float v = xx[ti] * yy[tj];
            if (ga::G.t[t].s > 0) gp[tk] += v; else gp[tk] -= v;
        }
#pragma unroll
        for (int t = 0; t < 81; t++) {
            const int ti = ga::J.t[t].i, tj = ga::J.t[t].j, tk = ga::J.t[t].k;
            const float v = xx[ti] * yy[tj];
            if (ga::J.t[t].s > 0) jn[tk] += v; else jn[tk] -= v;
        }
    }

    // Scheduling fence: no LDS op below may move above (and vice versa).
    // Makes the lo-overlay write legal w.r.t. every lane's lx/ly reads.
    __syncthreads();

    if (active) {
        // ---- stage results into overlay ----
#pragma unroll
        for (int k = 0; k < 4; k++)
            *reinterpret_cast<float4*>(lo + lane * OSTRIDE + k * 4) =
                make_float4(gp[4*k+0], gp[4*k+1], gp[4*k+2], gp[4*k+3]);
#pragma unroll
        for (int k = 0; k < 4; k++)
            *reinterpret_cast<float4*>(lo + lane * OSTRIDE + 16 + k * 4) =
                make_float4(r * jn[4*k+0], r * jn[4*k+1], r * jn[4*k+2], r * jn[4*k+3]);

        // ---- cooperative unit-stride store: 512 float4 per wave ----
        // write->read order pinned: access pairs may-alias per-thread.
        float4* go = reinterpret_cast<float4*>(out) + wbase * 8;
#pragma unroll
        for (int c = 0; c < 8; c++) {
            const int g  = lane + 64 * c;
            const int p  = g >> 3;
            const int ch = g & 7;
            go[g] = *reinterpret_cast<const float4*>(lo + p * OSTRIDE + ch * 4);
        }
    }
}

// Tail path (npts not divisible by 64) — scalar per-thread, same math.
__global__ __launch_bounds__(64)
void MVGeometricBilinear_tail(const float* __restrict__ x,
                              const float* __restrict__ y,
                              const float* __restrict__ ref,
                              float* __restrict__ out,
                              int start, int npts)
{
    int pt = start + blockIdx.x * 64 + threadIdx.x;
    if (pt >= npts) return;
    float xx[16], yy[16];
#pragma unroll
    for (int k = 0; k < 16; k++) { xx[k] = x[(size_t)pt*16+k]; yy[k] = y[(size_t)pt*16+k]; }
    const float r = ref[(size_t)pt*16+15];
    float gp[16] = {}, jn[16] = {};
#pragma unroll
    for (int t = 0; t < 192; t++) {
        const float v = xx[ga::G.t[t].i] * yy[ga::G.t[t].j];
        if (ga::G.t[t].s > 0) gp[ga::G.t[t].k] += v; else gp[ga::G.t[t].k] -= v;
    }
#pragma unroll
    for (int t = 0; t < 81; t++) {
        const float v = xx[ga::J.t[t].i] * yy[ga::J.t[t].j];
        if (ga::J.t[t].s > 0) jn[ga::J.t[t].k] += v; else jn[ga::J.t[t].k] -= v;
    }
#pragma unroll
    for (int k = 0; k < 16; k++) out[(size_t)pt*32+k] = gp[k];
#pragma unroll
    for (int k = 0; k < 16; k++) out[(size_t)pt*32+16+k] = r * jn[k];
}

extern "C" void kernel_launch(void* const* d_in, const int* in_sizes, int n_in,
                              void* d_out, int out_size, void* d_ws, size_t ws_size,
                              hipStream_t stream) {
    const float* x   = (const float*)d_in[0];
    const float* y   = (const float*)d_in[1];
    const float* ref = (const float*)d_in[2];
    float* out = (float*)d_out;

    const int npts   = in_sizes[0] / 16;      // B*T = 524288
    const int nwaves = npts / 64;             // full waves
    const int blocks = (nwaves + 1) / 2;      // 2 waves per 128-thread block

    MVGeometricBilinear_kernel<<<blocks, 128, 0, stream>>>(x, y, ref, out, nwaves);

    const int rem = npts - nwaves * 64;       // 0 for this shape
    if (rem > 0) {
        MVGeometricBilinear_tail<<<(rem + 63) / 64, 64, 0, stream>>>(
            x, y, ref, out, nwaves * 64, npts);
    }
}